// Round 4
// baseline (536.670 us; speedup 1.0000x reference)
//
#include <hip/hip_runtime.h>
#include <hip/hip_cooperative_groups.h>
#include <cstdint>

// ---------------------------------------------------------------------------
// GCN: 3 x [ h = relu( Ahat (h W) + b ) ], then log_softmax.
// Round 14: un-fuse r13 (agg_gemm lost 24 us/pair: LDS-capped occupancy +
// barrier coupling on a latency-limited gather). Back to verified aggregate
// + gemm_mfma. New: the 4-kernel CSR build + weight convert collapse into ONE
// cooperative kernel (256 blocks = 1/CU, phases split by grid.sync()):
//   phase0: convert W -> Wt bf16 + per-chunk histogram (LDS)
//   phase1: per-bucket scan over 256 chunks + atomicAdd ticket -> bucket base
//   phase2: scatter chunk edges to bucket-local packed queue (LDS cursors)
//   phase3: per-bucket finalize -> bd(beg,deg), dis, col (queue read once)
// Launches: 12 -> 7 (theory: ~9us/gap dominates the non-aggregate time).
// Fallback to split kernels if cooperative launch is rejected under capture.
// edge_index arrives as int32 (harness converts integer inputs).
// ---------------------------------------------------------------------------

#define D 128
#define NBMAX 800      // max dst buckets of 128 nodes (N <= 102400)
#define QCAP 4608      // LDS staging capacity per bucket in finalize
#define CB 256         // chunks == cooperative grid blocks

namespace cg = cooperative_groups;

typedef __attribute__((ext_vector_type(8))) short bf16x8;
typedef __attribute__((ext_vector_type(4))) float f32x4;

__device__ inline ushort f_to_bf(float f) {
    uint x = __float_as_uint(f);
    return (ushort)((x + 0x7fffu + ((x >> 16) & 1u)) >> 16);   // RNE
}
__device__ inline uint pack_bf2(float a, float b) {
    return (uint)f_to_bf(a) | ((uint)f_to_bf(b) << 16);
}
__device__ inline float bf_lo(uint u) { return __uint_as_float(u << 16); }
__device__ inline float bf_hi(uint u) { return __uint_as_float(u & 0xffff0000u); }

// ---------------- cooperative CSR build + weight convert ----------------

__global__ __launch_bounds__(256)
void csr_build(const int* __restrict__ ei,
               const float* __restrict__ W0, const float* __restrict__ W1,
               const float* __restrict__ W2, ushort* __restrict__ Wt0,
               ushort* __restrict__ Wt1, ushort* __restrict__ Wt2,
               int* __restrict__ hist, int* __restrict__ btotal,
               int* __restrict__ bbase, int* __restrict__ cursor,
               uint* __restrict__ queue, int2* __restrict__ bd,
               float* __restrict__ dis, int* __restrict__ col,
               int E, int N, int NB) {
    cg::grid_group grid = cg::this_grid();
    __shared__ int lh[NBMAX];        // phase0: hist, phase2: cursors
    __shared__ int s256[256];        // phase1 scan
    __shared__ uint qs[QCAP];        // phase3 bucket staging
    __shared__ int cnt[128], pre[128], run[128];

    int b = blockIdx.x, t = threadIdx.x;
    int CE = (E + CB - 1) / CB;      // edges per chunk

    // ---- phase 0: weight convert + chunk histogram ----
    {
        int i = b * 256 + t;                       // 65536 threads >= 49152
        if (i < 3 * D * D) {
            int which = i >> 14, r = i & 16383;
            const float* W = which == 0 ? W0 : (which == 1 ? W1 : W2);
            ushort* Wt = which == 0 ? Wt0 : (which == 1 ? Wt1 : Wt2);
            Wt[(r & 127) * D + (r >> 7)] = f_to_bf(W[r]);
        }
        if (b == 0 && t == 0) *cursor = 0;
        for (int i2 = t; i2 < NB; i2 += 256) lh[i2] = 0;
        __syncthreads();
        int e0 = b * CE, e1 = min(e0 + CE, E);
        for (int e = e0 + t; e < e1; e += 256)
            atomicAdd(&lh[ei[(size_t)E + e] >> 7], 1);
        __syncthreads();
        int* hrow = hist + (size_t)b * NB;
        for (int i2 = t; i2 < NB; i2 += 256) hrow[i2] = lh[i2];
    }
    grid.sync();

    // ---- phase 1: per-bucket scan over chunks + base ticket ----
    for (int g = b; g < NB; g += CB) {
        int v = hist[(size_t)t * NB + g];
        s256[t] = v;
        __syncthreads();
        for (int off = 1; off < 256; off <<= 1) {
            int u = (t >= off) ? s256[t - off] : 0;
            __syncthreads();
            s256[t] += u;
            __syncthreads();
        }
        hist[(size_t)t * NB + g] = s256[t] - v;    // exclusive within column
        if (t == 255) {
            btotal[g] = s256[255];
            bbase[g] = atomicAdd(cursor, s256[255]);   // one ticket per bucket
        }
        __syncthreads();
    }
    grid.sync();

    // ---- phase 2: scatter chunk b to bucket-local queue ----
    {
        const int* hrow = hist + (size_t)b * NB;
        for (int i = t; i < NB; i += 256) lh[i] = bbase[i] + hrow[i];
        __syncthreads();
        int e0 = b * CE, e1 = min(e0 + CE, E);
        for (int e = e0 + t; e < e1; e += 256) {
            int d = ei[(size_t)E + e];
            int s = ei[e];
            int slot = atomicAdd(&lh[d >> 7], 1);      // LDS atomic
            queue[slot] = ((uint)(d & 127) << 17) | (uint)s;   // needs N <= 131072
        }
    }
    grid.sync();

    // ---- phase 3: finalize buckets -> bd, dis, col ----
    for (int g = b; g < NB; g += CB) {
        int base = bbase[g], m = btotal[g];
        bool fits = (m <= QCAP);
        if (t < 128) { cnt[t] = 0; run[t] = 0; }
        __syncthreads();
        for (int i = t; i < m; i += 256) {
            uint e = queue[base + i];
            if (fits) qs[i] = e;
            atomicAdd(&cnt[e >> 17], 1);               // LDS atomic
        }
        __syncthreads();
        if (t < 128) pre[t] = cnt[t];
        __syncthreads();
        for (int off = 1; off < 128; off <<= 1) {
            int u = (t < 128 && t >= off) ? pre[t - off] : 0;
            __syncthreads();
            if (t < 128) pre[t] += u;                  // inclusive scan
            __syncthreads();
        }
        if (t < 128) {
            int node = (g << 7) + t;
            if (node < N) {
                bd[node] = make_int2(base + pre[t] - cnt[t], cnt[t]);
                dis[node] = rsqrtf((float)(cnt[t] + 1));   // self loop -> deg >= 1
            }
        }
        __syncthreads();
        for (int i = t; i < m; i += 256) {
            uint e = fits ? qs[i] : queue[base + i];
            int idx = (int)(e >> 17);
            int r = atomicAdd(&run[idx], 1);           // LDS atomic
            col[base + pre[idx] - cnt[idx] + r] = (int)(e & 0x1FFFFu);
        }
        __syncthreads();
    }
}

// ---------------- fallback split CSR kernels (non-cooperative path) --------

__global__ void hist_pass(const int* __restrict__ ei, int* __restrict__ hist,
                          int* __restrict__ cursor, int E, int NB) {
    __shared__ int lh[NBMAX];
    if (blockIdx.x == 0 && threadIdx.x == 0) *cursor = 0;
    for (int i = threadIdx.x; i < NB; i += 256) lh[i] = 0;
    __syncthreads();
    int CE = (E + CB - 1) / CB;
    int e0 = blockIdx.x * CE, e1 = min(e0 + CE, E);
    for (int e = e0 + threadIdx.x; e < e1; e += 256)
        atomicAdd(&lh[ei[(size_t)E + e] >> 7], 1);
    __syncthreads();
    int* hrow = hist + (size_t)blockIdx.x * NB;
    for (int i = threadIdx.x; i < NB; i += 256) hrow[i] = lh[i];
}

__global__ void col_scan(int* __restrict__ hist, int* __restrict__ btotal,
                         int* __restrict__ bbase, int* __restrict__ cursor, int NB) {
    __shared__ int s[256];
    int g = blockIdx.x, t = threadIdx.x;
    int v = hist[(size_t)t * NB + g];
    s[t] = v;
    __syncthreads();
    for (int off = 1; off < 256; off <<= 1) {
        int u = (t >= off) ? s[t - off] : 0;
        __syncthreads();
        s[t] += u;
        __syncthreads();
    }
    hist[(size_t)t * NB + g] = s[t] - v;
    if (t == 255) { btotal[g] = s[255]; bbase[g] = atomicAdd(cursor, s[255]); }
}

__global__ void scatter_pass(const int* __restrict__ ei, const int* __restrict__ hist,
                             const int* __restrict__ bbase, uint* __restrict__ queue,
                             int E, int NB) {
    __shared__ int loff[NBMAX];
    const int* hrow = hist + (size_t)blockIdx.x * NB;
    for (int i = threadIdx.x; i < NB; i += 256) loff[i] = bbase[i] + hrow[i];
    __syncthreads();
    int CE = (E + CB - 1) / CB;
    int e0 = blockIdx.x * CE, e1 = min(e0 + CE, E);
    for (int e = e0 + threadIdx.x; e < e1; e += 256) {
        int d = ei[(size_t)E + e];
        int s = ei[e];
        int slot = atomicAdd(&loff[d >> 7], 1);
        queue[slot] = ((uint)(d & 127) << 17) | (uint)s;
    }
}

__global__ void finalize_pass(const uint* __restrict__ queue, const int* __restrict__ bbase,
                              const int* __restrict__ btotal, int2* __restrict__ bd,
                              float* __restrict__ dis, int* __restrict__ col, int N) {
    __shared__ uint qs[QCAP];
    __shared__ int cnt[128], pre[128], run[128];
    int g = blockIdx.x, t = threadIdx.x;
    int base = bbase[g], m = btotal[g];
    bool fits = (m <= QCAP);
    if (t < 128) { cnt[t] = 0; run[t] = 0; }
    __syncthreads();
    for (int i = t; i < m; i += 256) {
        uint e = queue[base + i];
        if (fits) qs[i] = e;
        atomicAdd(&cnt[e >> 17], 1);
    }
    __syncthreads();
    if (t < 128) pre[t] = cnt[t];
    __syncthreads();
    for (int off = 1; off < 128; off <<= 1) {
        int u = (t < 128 && t >= off) ? pre[t - off] : 0;
        __syncthreads();
        if (t < 128) pre[t] += u;
        __syncthreads();
    }
    if (t < 128) {
        int node = (g << 7) + t;
        if (node < N) {
            bd[node] = make_int2(base + pre[t] - cnt[t], cnt[t]);
            dis[node] = rsqrtf((float)(cnt[t] + 1));
        }
    }
    __syncthreads();
    for (int i = t; i < m; i += 256) {
        uint e = fits ? qs[i] : queue[base + i];
        int idx = (int)(e >> 17);
        int r = atomicAdd(&run[idx], 1);
        col[base + pre[idx] - cnt[idx] + r] = (int)(e & 0x1FFFFu);
    }
}

__global__ void convert_w3(const float* __restrict__ W0, const float* __restrict__ W1,
                           const float* __restrict__ W2, ushort* __restrict__ Wt0,
                           ushort* __restrict__ Wt1, ushort* __restrict__ Wt2) {
    int which = blockIdx.x >> 6;
    int i = (blockIdx.x & 63) * 256 + threadIdx.x;
    const float* W = which == 0 ? W0 : (which == 1 ? W1 : W2);
    ushort* Wt = which == 0 ? Wt0 : (which == 1 ? Wt1 : Wt2);
    int k = i >> 7, nn = i & 127;
    Wt[nn * D + k] = f_to_bf(W[i]);
}

// ---------------- GEMM: G[n,128] = dis[row] * (X[n,128] @ W), MFMA ----------
// 256 threads = 4 waves; wave computes 32 rows x 128 cols. Wt staged once per
// block into LDS in frag-major swizzled order (lane-contiguous ds_read_b128).
template <int F32IN>
__global__ __launch_bounds__(256)
void gemm_mfma(const void* __restrict__ Xv, const ushort* __restrict__ Wt,
               const float* __restrict__ dis, ushort* __restrict__ G, int n) {
    __shared__ ushort Bs[32 * 64 * 8];   // 32 KB
    int tid = threadIdx.x;
    int wave = tid >> 6, lane = tid & 63;
    int lr = lane & 15, quad = lane >> 4;
    int rowbase = blockIdx.x * 128 + wave * 32;

    for (int s = tid; s < 2048; s += 256) {
        int g = s >> 6, l = s & 63;
        int kk = g >> 3, nt = g & 7;
        int srow = nt * 16 + (l & 15);
        int scol = kk * 32 + (l >> 4) * 8;
        ((uint4*)Bs)[s] = *(const uint4*)(Wt + srow * D + scol);
    }
    __syncthreads();

    int ar0 = min(rowbase + lr, n - 1);
    int ar1 = min(rowbase + 16 + lr, n - 1);

    f32x4 acc[2][8];
#pragma unroll
    for (int rt = 0; rt < 2; rt++)
#pragma unroll
        for (int nt = 0; nt < 8; nt++) acc[rt][nt] = (f32x4){0.f, 0.f, 0.f, 0.f};

#pragma unroll
    for (int kk = 0; kk < 4; kk++) {
        bf16x8 a0, a1;
        if (F32IN) {
            const float* X = (const float*)Xv;
            const float* p0 = X + (size_t)ar0 * D + kk * 32 + quad * 8;
            const float* p1 = X + (size_t)ar1 * D + kk * 32 + quad * 8;
            float4 u0 = ((const float4*)p0)[0], v0 = ((const float4*)p0)[1];
            float4 u1 = ((const float4*)p1)[0], v1 = ((const float4*)p1)[1];
            a0 = (bf16x8){(short)f_to_bf(u0.x), (short)f_to_bf(u0.y), (short)f_to_bf(u0.z), (short)f_to_bf(u0.w),
                          (short)f_to_bf(v0.x), (short)f_to_bf(v0.y), (short)f_to_bf(v0.z), (short)f_to_bf(v0.w)};
            a1 = (bf16x8){(short)f_to_bf(u1.x), (short)f_to_bf(u1.y), (short)f_to_bf(u1.z), (short)f_to_bf(u1.w),
                          (short)f_to_bf(v1.x), (short)f_to_bf(v1.y), (short)f_to_bf(v1.z), (short)f_to_bf(v1.w)};
        } else {
            const ushort* X = (const ushort*)Xv;
            a0 = ((const bf16x8*)(X + (size_t)ar0 * D))[kk * 4 + quad];
            a1 = ((const bf16x8*)(X + (size_t)ar1 * D))[kk * 4 + quad];
        }
#pragma unroll
        for (int nt = 0; nt < 8; nt++) {
            bf16x8 b = ((const bf16x8*)Bs)[(kk * 8 + nt) * 64 + lane];
            acc[0][nt] = __builtin_amdgcn_mfma_f32_16x16x32_bf16(a0, b, acc[0][nt], 0, 0, 0);
            acc[1][nt] = __builtin_amdgcn_mfma_f32_16x16x32_bf16(a1, b, acc[1][nt], 0, 0, 0);
        }
    }

#pragma unroll
    for (int rt = 0; rt < 2; rt++) {
#pragma unroll
        for (int r = 0; r < 4; r++) {
            int row = rowbase + rt * 16 + quad * 4 + r;
            if (row < n) {
                float dsc = dis[row];
#pragma unroll
                for (int nt = 0; nt < 8; nt++)
                    G[(size_t)row * D + nt * 16 + lr] = f_to_bf(dsc * acc[rt][nt][r]);
            }
        }
    }
}

// ---------------- Aggregation ----------------
// G rows pre-scaled by dis[src]. out[i] = act( dis[i]*(sum G[s] + G[i]) + b ).
// QUARTER-wave (16 lanes x uint4 = 8 bf16) per node; edge loop unrolled x8
// -> 8 KB of gathers in flight per wave. MODE 0: relu->bf16. MODE 1: +lsm->f32.
template <int MODE>
__global__ __launch_bounds__(256)
void aggregate(const ushort* __restrict__ Gv, const float* __restrict__ dis,
               const int2* __restrict__ bd, const int* __restrict__ col,
               const float* __restrict__ bias, void* __restrict__ outv, int n) {
    int node = blockIdx.x * 16 + (threadIdx.x >> 4);
    if (node >= n) return;
    int lane = threadIdx.x & 15;
    const uint4* base = (const uint4*)Gv;

    uint4 u = base[(size_t)node * 16 + lane];
    float a0 = bf_lo(u.x), a1 = bf_hi(u.x), a2 = bf_lo(u.y), a3 = bf_hi(u.y);
    float a4 = bf_lo(u.z), a5 = bf_hi(u.z), a6 = bf_lo(u.w), a7 = bf_hi(u.w);

    int2 be = bd[node];
    int beg = be.x, end = be.x + be.y;
    int j = beg;
    for (; j + 8 <= end; j += 8) {
        uint4 v0 = base[(size_t)col[j + 0] * 16 + lane];
        uint4 v1 = base[(size_t)col[j + 1] * 16 + lane];
        uint4 v2 = base[(size_t)col[j + 2] * 16 + lane];
        uint4 v3 = base[(size_t)col[j + 3] * 16 + lane];
        uint4 v4 = base[(size_t)col[j + 4] * 16 + lane];
        uint4 v5 = base[(size_t)col[j + 5] * 16 + lane];
        uint4 v6 = base[(size_t)col[j + 6] * 16 + lane];
        uint4 v7 = base[(size_t)col[j + 7] * 16 + lane];
        a0 += bf_lo(v0.x) + bf_lo(v1.x) + bf_lo(v2.x) + bf_lo(v3.x)
            + bf_lo(v4.x) + bf_lo(v5.x) + bf_lo(v6.x) + bf_lo(v7.x);
        a1 += bf_hi(v0.x) + bf_hi(v1.x) + bf_hi(v2.x) + bf_hi(v3.x)
            + bf_hi(v4.x) + bf_hi(v5.x) + bf_hi(v6.x) + bf_hi(v7.x);
        a2 += bf_lo(v0.y) + bf_lo(v1.y) + bf_lo(v2.y) + bf_lo(v3.y)
            + bf_lo(v4.y) + bf_lo(v5.y) + bf_lo(v6.y) + bf_lo(v7.y);
        a3 += bf_hi(v0.y) + bf_hi(v1.y) + bf_hi(v2.y) + bf_hi(v3.y)
            + bf_hi(v4.y) + bf_hi(v5.y) + bf_hi(v6.y) + bf_hi(v7.y);
        a4 += bf_lo(v0.z) + bf_lo(v1.z) + bf_lo(v2.z) + bf_lo(v3.z)
            + bf_lo(v4.z) + bf_lo(v5.z) + bf_lo(v6.z) + bf_lo(v7.z);
        a5 += bf_hi(v0.z) + bf_hi(v1.z) + bf_hi(v2.z) + bf_hi(v3.z)
            + bf_hi(v4.z) + bf_hi(v5.z) + bf_hi(v6.z) + bf_hi(v7.z);
        a6 += bf_lo(v0.w) + bf_lo(v1.w) + bf_lo(v2.w) + bf_lo(v3.w)
            + bf_lo(v4.w) + bf_lo(v5.w) + bf_lo(v6.w) + bf_lo(v7.w);
        a7 += bf_hi(v0.w) + bf_hi(v1.w) + bf_hi(v2.w) + bf_hi(v3.w)
            + bf_hi(v4.w) + bf_hi(v5.w) + bf_hi(v6.w) + bf_hi(v7.w);
    }
    for (; j < end; j++) {
        uint4 v = base[(size_t)col[j] * 16 + lane];
        a0 += bf_lo(v.x); a1 += bf_hi(v.x); a2 += bf_lo(v.y); a3 += bf_hi(v.y);
        a4 += bf_lo(v.z); a5 += bf_hi(v.z); a6 += bf_lo(v.w); a7 += bf_hi(v.w);
    }

    float di = dis[node];
    float4 bA = ((const float4*)bias)[lane * 2];
    float4 bB = ((const float4*)bias)[lane * 2 + 1];
    a0 = fmaxf(di * a0 + bA.x, 0.f); a1 = fmaxf(di * a1 + bA.y, 0.f);
    a2 = fmaxf(di * a2 + bA.z, 0.f); a3 = fmaxf(di * a3 + bA.w, 0.f);
    a4 = fmaxf(di * a4 + bB.x, 0.f); a5 = fmaxf(di * a5 + bB.y, 0.f);
    a6 = fmaxf(di * a6 + bB.z, 0.f); a7 = fmaxf(di * a7 + bB.w, 0.f);

    if (MODE == 1) {
        float m = fmaxf(fmaxf(fmaxf(a0, a1), fmaxf(a2, a3)),
                        fmaxf(fmaxf(a4, a5), fmaxf(a6, a7)));
        for (int off = 8; off > 0; off >>= 1) m = fmaxf(m, __shfl_xor(m, off, 16));
        float e = __expf(a0 - m) + __expf(a1 - m) + __expf(a2 - m) + __expf(a3 - m)
                + __expf(a4 - m) + __expf(a5 - m) + __expf(a6 - m) + __expf(a7 - m);
        for (int off = 8; off > 0; off >>= 1) e += __shfl_xor(e, off, 16);
        float ls = m + __logf(e);
        ((float4*)outv)[(size_t)node * 32 + lane * 2]     = make_float4(a0 - ls, a1 - ls, a2 - ls, a3 - ls);
        ((float4*)outv)[(size_t)node * 32 + lane * 2 + 1] = make_float4(a4 - ls, a5 - ls, a6 - ls, a7 - ls);
    } else {
        ((uint4*)outv)[(size_t)node * 16 + lane] =
            make_uint4(pack_bf2(a0, a1), pack_bf2(a2, a3), pack_bf2(a4, a5), pack_bf2(a6, a7));
    }
}

// ---------------- launcher ----------------

static inline size_t align256(size_t x) { return (x + 255) & ~(size_t)255; }

extern "C" void kernel_launch(void* const* d_in, const int* in_sizes, int n_in,
                              void* d_out, int out_size, void* d_ws, size_t ws_size,
                              hipStream_t stream) {
    const float* x  = (const float*)d_in[0];
    const int*   ei = (const int*)d_in[1];      // int32 (harness-converted)
    const float* W0 = (const float*)d_in[2];
    const float* W1 = (const float*)d_in[3];
    const float* W2 = (const float*)d_in[4];
    const float* b0 = (const float*)d_in[5];
    const float* b1 = (const float*)d_in[6];
    const float* b2 = (const float*)d_in[7];
    float* out      = (float*)d_out;

    const int N = in_sizes[0] / D;
    const int E = in_sizes[1] / 2;
    const int NB = (N + 127) >> 7;              // dst buckets (<= NBMAX)

    // workspace (~60 MB)
    char* ws = (char*)d_ws;
    size_t off = 0;
    float*  dis      = (float*)(ws + off);  off = align256(off + (size_t)N * 4);
    int2*   bd       = (int2*)(ws + off);   off = align256(off + (size_t)N * 8);
    int*    hist     = (int*)(ws + off);    off = align256(off + (size_t)CB * NB * 4);
    int*    btotal   = (int*)(ws + off);    off = align256(off + (size_t)NB * 4);
    int*    bbase    = (int*)(ws + off);    off = align256(off + (size_t)NB * 4);
    int*    cursor   = (int*)(ws + off);    off = align256(off + 4);
    ushort* Wt0      = (ushort*)(ws + off); off = align256(off + (size_t)D * D * 2);
    ushort* Wt1      = (ushort*)(ws + off); off = align256(off + (size_t)D * D * 2);
    ushort* Wt2      = (ushort*)(ws + off); off = align256(off + (size_t)D * D * 2);
    int*    col      = (int*)(ws + off);    off = align256(off + (size_t)E * 4);
    ushort* bufA     = (ushort*)(ws + off); off = align256(off + (size_t)N * D * 2);
    ushort* bufB     = (ushort*)(ws + off); off = align256(off + (size_t)N * D * 2);
    ushort* dhead    = (ushort*)d_out;      // 25.6 MB of d_out; dead before final write
    uint*   queue    = (uint*)bufA;         // E*4B = 6.4MB, dead before aggregate-0
    (void)ws_size;

    // --- CSR build + weight convert: one cooperative kernel ---
    {
        const int* ei_ = ei; const float *W0_ = W0, *W1_ = W1, *W2_ = W2;
        ushort *Wt0_ = Wt0, *Wt1_ = Wt1, *Wt2_ = Wt2;
        int *hist_ = hist, *btotal_ = btotal, *bbase_ = bbase, *cursor_ = cursor;
        uint* queue_ = queue; int2* bd_ = bd; float* dis_ = dis; int* col_ = col;
        int E_ = E, N_ = N, NB_ = NB;
        void* params[] = {&ei_, &W0_, &W1_, &W2_, &Wt0_, &Wt1_, &Wt2_,
                          &hist_, &btotal_, &bbase_, &cursor_, &queue_,
                          &bd_, &dis_, &col_, &E_, &N_, &NB_};
        hipError_t cerr = hipLaunchCooperativeKernel((void*)csr_build,
                                                     dim3(CB), dim3(256),
                                                     params, 0, stream);
        if (cerr != hipSuccess) {
            // fallback: split kernels (same data layout)
            hist_pass<<<CB, 256, 0, stream>>>(ei, hist, cursor, E, NB);
            col_scan<<<NB, 256, 0, stream>>>(hist, btotal, bbase, cursor, NB);
            scatter_pass<<<CB, 256, 0, stream>>>(ei, hist, bbase, queue, E, NB);
            finalize_pass<<<NB, 256, 0, stream>>>(queue, bbase, btotal, bd, dis, col, N);
            convert_w3<<<192, 256, 0, stream>>>(W0, W1, W2, Wt0, Wt1, Wt2);
        }
    }

    const int gemmBlocks = (N + 127) / 128;
    const int aggBlocks  = (N + 15) / 16;

    // --- layer 0: x(fp32) @ W0 -> dhead; agg -> bufA ---
    gemm_mfma<1><<<gemmBlocks, 256, 0, stream>>>(x, Wt0, dis, dhead, N);
    aggregate<0><<<aggBlocks, 256, 0, stream>>>(dhead, dis, bd, col, b0, bufA, N);
    // --- layer 1: bufA @ W1 -> bufB; agg -> dhead ---
    gemm_mfma<0><<<gemmBlocks, 256, 0, stream>>>(bufA, Wt1, dis, bufB, N);
    aggregate<0><<<aggBlocks, 256, 0, stream>>>(bufB, dis, bd, col, b1, dhead, N);
    // --- layer 2: dhead @ W2 -> bufA; agg + log_softmax -> out ---
    gemm_mfma<0><<<gemmBlocks, 256, 0, stream>>>(dhead, Wt2, dis, bufA, N);
    aggregate<1><<<aggBlocks, 256, 0, stream>>>(bufA, dis, bd, col, b2, out, N);
}

// Round 5
// 422.903 us; speedup vs baseline: 1.2690x; 1.2690x over previous
//
#include <hip/hip_runtime.h>
#include <cstdint>

// ---------------------------------------------------------------------------
// GCN: 3 x [ h = relu( Ahat (h W) + b ) ], then log_softmax.
// Round 15: fusion retry with the r13 occupancy bug fixed. agg_gemm now reads
// B-fragments DIRECTLY from global Wt (L2-hot 32KB, same address stream for
// every block) instead of staging into 32KB LDS -> LDS 36KB->4KB, ~8 blocks/CU
// resident (r13: ~4), straggler tails hidden. As (16x128 bf16, XOR-swizzled)
// is the only LDS. r14 lesson: no cooperative launch (1 block/CU strangles
// memory phases). r11 lesson: no returned global atomics. CSR = r13's
// 4-kernel histogram sort (ticketed bucket bases, packed 4B queue, LDS-staged
// finalize). Pipeline: CSR(4) + convert + gemm0 + fused1 + fused2 + aggLSM
// = 9 launches (r12: 12).
// edge_index arrives as int32 (harness converts integer inputs).
// ---------------------------------------------------------------------------

#define D 128
#define NBMAX 800      // max dst buckets of 128 nodes (N <= 102400)
#define QCAP 4608      // LDS staging capacity per bucket in finalize
#define CB 256         // histogram/scatter chunks

typedef __attribute__((ext_vector_type(8))) short bf16x8;
typedef __attribute__((ext_vector_type(4))) float f32x4;

__device__ inline ushort f_to_bf(float f) {
    uint x = __float_as_uint(f);
    return (ushort)((x + 0x7fffu + ((x >> 16) & 1u)) >> 16);   // RNE
}
__device__ inline uint pack_bf2(float a, float b) {
    return (uint)f_to_bf(a) | ((uint)f_to_bf(b) << 16);
}
__device__ inline float bf_lo(uint u) { return __uint_as_float(u << 16); }
__device__ inline float bf_hi(uint u) { return __uint_as_float(u & 0xffff0000u); }

// ---------------- CSR build (histogram sort; LDS atomics only) -------------

__global__ void hist_pass(const int* __restrict__ ei, int* __restrict__ hist,
                          int* __restrict__ cursor, int E, int NB) {
    __shared__ int lh[NBMAX];
    if (blockIdx.x == 0 && threadIdx.x == 0) *cursor = 0;
    for (int i = threadIdx.x; i < NB; i += 256) lh[i] = 0;
    __syncthreads();
    int CE = (E + CB - 1) / CB;
    int e0 = blockIdx.x * CE, e1 = min(e0 + CE, E);
    for (int e = e0 + threadIdx.x; e < e1; e += 256)
        atomicAdd(&lh[ei[(size_t)E + e] >> 7], 1);
    __syncthreads();
    int* hrow = hist + (size_t)blockIdx.x * NB;
    for (int i = threadIdx.x; i < NB; i += 256) hrow[i] = lh[i];
}

__global__ void col_scan(int* __restrict__ hist, int* __restrict__ btotal,
                         int* __restrict__ bbase, int* __restrict__ cursor, int NB) {
    __shared__ int s[256];
    int g = blockIdx.x, t = threadIdx.x;
    int v = hist[(size_t)t * NB + g];
    s[t] = v;
    __syncthreads();
    for (int off = 1; off < 256; off <<= 1) {
        int u = (t >= off) ? s[t - off] : 0;
        __syncthreads();
        s[t] += u;
        __syncthreads();
    }
    hist[(size_t)t * NB + g] = s[t] - v;              // exclusive within column
    if (t == 255) { btotal[g] = s[255]; bbase[g] = atomicAdd(cursor, s[255]); }
}

__global__ void scatter_pass(const int* __restrict__ ei, const int* __restrict__ hist,
                             const int* __restrict__ bbase, uint* __restrict__ queue,
                             int E, int NB) {
    __shared__ int loff[NBMAX];
    const int* hrow = hist + (size_t)blockIdx.x * NB;
    for (int i = threadIdx.x; i < NB; i += 256) loff[i] = bbase[i] + hrow[i];
    __syncthreads();
    int CE = (E + CB - 1) / CB;
    int e0 = blockIdx.x * CE, e1 = min(e0 + CE, E);
    for (int e = e0 + threadIdx.x; e < e1; e += 256) {
        int d = ei[(size_t)E + e];
        int s = ei[e];
        int slot = atomicAdd(&loff[d >> 7], 1);       // LDS atomic
        queue[slot] = ((uint)(d & 127) << 17) | (uint)s;   // needs N <= 131072
    }
}

__global__ void finalize_pass(const uint* __restrict__ queue, const int* __restrict__ bbase,
                              const int* __restrict__ btotal, int2* __restrict__ bd,
                              float* __restrict__ dis, int* __restrict__ col, int N) {
    __shared__ uint qs[QCAP];
    __shared__ int cnt[128], pre[128], run[128];
    int g = blockIdx.x, t = threadIdx.x;
    int base = bbase[g], m = btotal[g];
    bool fits = (m <= QCAP);
    if (t < 128) { cnt[t] = 0; run[t] = 0; }
    __syncthreads();
    for (int i = t; i < m; i += 256) {
        uint e = queue[base + i];
        if (fits) qs[i] = e;
        atomicAdd(&cnt[e >> 17], 1);                  // LDS atomic
    }
    __syncthreads();
    if (t < 128) pre[t] = cnt[t];
    __syncthreads();
    for (int off = 1; off < 128; off <<= 1) {
        int u = (t < 128 && t >= off) ? pre[t - off] : 0;
        __syncthreads();
        if (t < 128) pre[t] += u;                     // inclusive scan
        __syncthreads();
    }
    if (t < 128) {
        int node = (g << 7) + t;
        if (node < N) {
            bd[node] = make_int2(base + pre[t] - cnt[t], cnt[t]);
            dis[node] = rsqrtf((float)(cnt[t] + 1));  // self loop -> deg >= 1
        }
    }
    __syncthreads();
    for (int i = t; i < m; i += 256) {
        uint e = fits ? qs[i] : queue[base + i];
        int idx = (int)(e >> 17);
        int r = atomicAdd(&run[idx], 1);              // LDS atomic
        col[base + pre[idx] - cnt[idx] + r] = (int)(e & 0x1FFFFu);
    }
}

// W fp32 [k][n] -> Wt bf16 [n][k], all three weights in one launch
__global__ void convert_w3(const float* __restrict__ W0, const float* __restrict__ W1,
                           const float* __restrict__ W2, ushort* __restrict__ Wt0,
                           ushort* __restrict__ Wt1, ushort* __restrict__ Wt2) {
    int which = blockIdx.x >> 6;   // 64 blocks (16384 elems) per weight
    int i = (blockIdx.x & 63) * 256 + threadIdx.x;
    const float* W = which == 0 ? W0 : (which == 1 ? W1 : W2);
    ushort* Wt = which == 0 ? Wt0 : (which == 1 ? Wt1 : Wt2);
    int k = i >> 7, nn = i & 127;
    Wt[nn * D + k] = f_to_bf(W[i]);
}

// ---------------- GEMM: G[n,128] = dis[row] * (X[n,128] @ W), MFMA ----------
// 256 threads = 4 waves; wave computes 32 rows x 128 cols. Wt staged once per
// block into LDS in frag-major swizzled order (lane-contiguous ds_read_b128).
template <int F32IN>
__global__ __launch_bounds__(256)
void gemm_mfma(const void* __restrict__ Xv, const ushort* __restrict__ Wt,
               const float* __restrict__ dis, ushort* __restrict__ G, int n) {
    __shared__ ushort Bs[32 * 64 * 8];   // 32 KB
    int tid = threadIdx.x;
    int wave = tid >> 6, lane = tid & 63;
    int lr = lane & 15, quad = lane >> 4;
    int rowbase = blockIdx.x * 128 + wave * 32;

    for (int s = tid; s < 2048; s += 256) {
        int g = s >> 6, l = s & 63;
        int kk = g >> 3, nt = g & 7;
        int srow = nt * 16 + (l & 15);
        int scol = kk * 32 + (l >> 4) * 8;
        ((uint4*)Bs)[s] = *(const uint4*)(Wt + srow * D + scol);
    }
    __syncthreads();

    int ar0 = min(rowbase + lr, n - 1);
    int ar1 = min(rowbase + 16 + lr, n - 1);

    f32x4 acc[2][8];
#pragma unroll
    for (int rt = 0; rt < 2; rt++)
#pragma unroll
        for (int nt = 0; nt < 8; nt++) acc[rt][nt] = (f32x4){0.f, 0.f, 0.f, 0.f};

#pragma unroll
    for (int kk = 0; kk < 4; kk++) {
        bf16x8 a0, a1;
        if (F32IN) {
            const float* X = (const float*)Xv;
            const float* p0 = X + (size_t)ar0 * D + kk * 32 + quad * 8;
            const float* p1 = X + (size_t)ar1 * D + kk * 32 + quad * 8;
            float4 u0 = ((const float4*)p0)[0], v0 = ((const float4*)p0)[1];
            float4 u1 = ((const float4*)p1)[0], v1 = ((const float4*)p1)[1];
            a0 = (bf16x8){(short)f_to_bf(u0.x), (short)f_to_bf(u0.y), (short)f_to_bf(u0.z), (short)f_to_bf(u0.w),
                          (short)f_to_bf(v0.x), (short)f_to_bf(v0.y), (short)f_to_bf(v0.z), (short)f_to_bf(v0.w)};
            a1 = (bf16x8){(short)f_to_bf(u1.x), (short)f_to_bf(u1.y), (short)f_to_bf(u1.z), (short)f_to_bf(u1.w),
                          (short)f_to_bf(v1.x), (short)f_to_bf(v1.y), (short)f_to_bf(v1.z), (short)f_to_bf(v1.w)};
        } else {
            const ushort* X = (const ushort*)Xv;
            a0 = ((const bf16x8*)(X + (size_t)ar0 * D))[kk * 4 + quad];
            a1 = ((const bf16x8*)(X + (size_t)ar1 * D))[kk * 4 + quad];
        }
#pragma unroll
        for (int nt = 0; nt < 8; nt++) {
            bf16x8 b = ((const bf16x8*)Bs)[(kk * 8 + nt) * 64 + lane];
            acc[0][nt] = __builtin_amdgcn_mfma_f32_16x16x32_bf16(a0, b, acc[0][nt], 0, 0, 0);
            acc[1][nt] = __builtin_amdgcn_mfma_f32_16x16x32_bf16(a1, b, acc[1][nt], 0, 0, 0);
        }
    }

#pragma unroll
    for (int rt = 0; rt < 2; rt++) {
#pragma unroll
        for (int r = 0; r < 4; r++) {
            int row = rowbase + rt * 16 + quad * 4 + r;
            if (row < n) {
                float dsc = dis[row];
#pragma unroll
                for (int nt = 0; nt < 8; nt++)
                    G[(size_t)row * D + nt * 16 + lr] = f_to_bf(dsc * acc[rt][nt][r]);
            }
        }
    }
}

// ---------------- FUSED aggregate(layer k) + GEMM(layer k+1), lite ---------
// Block = 16 nodes. Phase 1: verified quarter-wave gather -> bias+relu ->
// bf16 row into XOR-swizzled 4KB LDS As. Phase 2: 16-row MFMA tile with
// B-frags read DIRECTLY from global Wt (L2-hot; same addresses per block):
// b(nt,kk) = Wt[(nt*16+lr)*D + kk*32 + quad*8 ..+8]  (== r13's Bs contents).
// Output rows pre-scaled by dis[row] for the next aggregate. Only 4KB LDS ->
// ~8 blocks/CU resident (r13 failure was 36KB -> 4/CU + straggler coupling).
__global__ __launch_bounds__(256)
void agg_gemm(const ushort* __restrict__ Gv, const float* __restrict__ dis,
              const int2* __restrict__ bd, const int* __restrict__ col,
              const float* __restrict__ bias, const ushort* __restrict__ Wt,
              ushort* __restrict__ Gout, int n) {
    __shared__ ushort As[16 * 128];      // 4 KB, XOR-swizzled 16B slots
    int tid = threadIdx.x;
    int r16 = tid >> 4, lane16 = tid & 15;
    int node = blockIdx.x * 16 + r16;

    // ---- phase 1: aggregate (verified quarter-wave loop) ----
    float a0 = 0.f, a1 = 0.f, a2 = 0.f, a3 = 0.f,
          a4 = 0.f, a5 = 0.f, a6 = 0.f, a7 = 0.f;
    if (node < n) {
        const uint4* base = (const uint4*)Gv;
        uint4 u = base[(size_t)node * 16 + lane16];
        a0 = bf_lo(u.x); a1 = bf_hi(u.x); a2 = bf_lo(u.y); a3 = bf_hi(u.y);
        a4 = bf_lo(u.z); a5 = bf_hi(u.z); a6 = bf_lo(u.w); a7 = bf_hi(u.w);

        int2 be = bd[node];
        int beg = be.x, end = be.x + be.y;
        int j = beg;
        for (; j + 8 <= end; j += 8) {
            uint4 v0 = base[(size_t)col[j + 0] * 16 + lane16];
            uint4 v1 = base[(size_t)col[j + 1] * 16 + lane16];
            uint4 v2 = base[(size_t)col[j + 2] * 16 + lane16];
            uint4 v3 = base[(size_t)col[j + 3] * 16 + lane16];
            uint4 v4 = base[(size_t)col[j + 4] * 16 + lane16];
            uint4 v5 = base[(size_t)col[j + 5] * 16 + lane16];
            uint4 v6 = base[(size_t)col[j + 6] * 16 + lane16];
            uint4 v7 = base[(size_t)col[j + 7] * 16 + lane16];
            a0 += bf_lo(v0.x) + bf_lo(v1.x) + bf_lo(v2.x) + bf_lo(v3.x)
                + bf_lo(v4.x) + bf_lo(v5.x) + bf_lo(v6.x) + bf_lo(v7.x);
            a1 += bf_hi(v0.x) + bf_hi(v1.x) + bf_hi(v2.x) + bf_hi(v3.x)
                + bf_hi(v4.x) + bf_hi(v5.x) + bf_hi(v6.x) + bf_hi(v7.x);
            a2 += bf_lo(v0.y) + bf_lo(v1.y) + bf_lo(v2.y) + bf_lo(v3.y)
                + bf_lo(v4.y) + bf_lo(v5.y) + bf_lo(v6.y) + bf_lo(v7.y);
            a3 += bf_hi(v0.y) + bf_hi(v1.y) + bf_hi(v2.y) + bf_hi(v3.y)
                + bf_hi(v4.y) + bf_hi(v5.y) + bf_hi(v6.y) + bf_hi(v7.y);
            a4 += bf_lo(v0.z) + bf_lo(v1.z) + bf_lo(v2.z) + bf_lo(v3.z)
                + bf_lo(v4.z) + bf_lo(v5.z) + bf_lo(v6.z) + bf_lo(v7.z);
            a5 += bf_hi(v0.z) + bf_hi(v1.z) + bf_hi(v2.z) + bf_hi(v3.z)
                + bf_hi(v4.z) + bf_hi(v5.z) + bf_hi(v6.z) + bf_hi(v7.z);
            a6 += bf_lo(v0.w) + bf_lo(v1.w) + bf_lo(v2.w) + bf_lo(v3.w)
                + bf_lo(v4.w) + bf_lo(v5.w) + bf_lo(v6.w) + bf_lo(v7.w);
            a7 += bf_hi(v0.w) + bf_hi(v1.w) + bf_hi(v2.w) + bf_hi(v3.w)
                + bf_hi(v4.w) + bf_hi(v5.w) + bf_hi(v6.w) + bf_hi(v7.w);
        }
        for (; j < end; j++) {
            uint4 v = base[(size_t)col[j] * 16 + lane16];
            a0 += bf_lo(v.x); a1 += bf_hi(v.x); a2 += bf_lo(v.y); a3 += bf_hi(v.y);
            a4 += bf_lo(v.z); a5 += bf_hi(v.z); a6 += bf_lo(v.w); a7 += bf_hi(v.w);
        }

        float di = dis[node];
        float4 bA = ((const float4*)bias)[lane16 * 2];
        float4 bB = ((const float4*)bias)[lane16 * 2 + 1];
        a0 = fmaxf(di * a0 + bA.x, 0.f); a1 = fmaxf(di * a1 + bA.y, 0.f);
        a2 = fmaxf(di * a2 + bA.z, 0.f); a3 = fmaxf(di * a3 + bA.w, 0.f);
        a4 = fmaxf(di * a4 + bB.x, 0.f); a5 = fmaxf(di * a5 + bB.y, 0.f);
        a6 = fmaxf(di * a6 + bB.z, 0.f); a7 = fmaxf(di * a7 + bB.w, 0.f);
    }

    // write h row to As: logical 16B slot = lane16 of row r16; phys = slot^(r&7)
    {
        uint4 packed = make_uint4(pack_bf2(a0, a1), pack_bf2(a2, a3),
                                  pack_bf2(a4, a5), pack_bf2(a6, a7));
        uint woff = ((uint)(r16 * 256 + lane16 * 16)) ^ ((uint)(r16 & 7) << 4);
        *(uint4*)((char*)As + woff) = packed;
    }
    __syncthreads();

    // ---- phase 2: 16-row GEMM; B direct from global Wt (L2-hot) ----
    int wave = tid >> 6, lane = tid & 63;
    int lr = lane & 15, quad = lane >> 4;
    f32x4 acc0 = (f32x4){0.f, 0.f, 0.f, 0.f};
    f32x4 acc1 = (f32x4){0.f, 0.f, 0.f, 0.f};
    const ushort* wb0 = Wt + ((wave * 2 + 0) * 16 + lr) * D + quad * 8;
    const ushort* wb1 = Wt + ((wave * 2 + 1) * 16 + lr) * D + quad * 8;
#pragma unroll
    for (int kk = 0; kk < 4; kk++) {
        uint roff = ((uint)(lr * 256 + (kk * 4 + quad) * 16)) ^ ((uint)(lr & 7) << 4);
        bf16x8 a = *(const bf16x8*)((const char*)As + roff);
        bf16x8 b0 = *(const bf16x8*)(wb0 + kk * 32);
        bf16x8 b1 = *(const bf16x8*)(wb1 + kk * 32);
        acc0 = __builtin_amdgcn_mfma_f32_16x16x32_bf16(a, b0, acc0, 0, 0, 0);
        acc1 = __builtin_amdgcn_mfma_f32_16x16x32_bf16(a, b1, acc1, 0, 0, 0);
    }

    // epilogue (verified): row = quad*4+r, col = (wave*2+x)*16+lr; scale by dis
#pragma unroll
    for (int r = 0; r < 4; r++) {
        int row = blockIdx.x * 16 + quad * 4 + r;
        if (row < n) {
            float dsc = dis[row];
            Gout[(size_t)row * D + (wave * 2 + 0) * 16 + lr] = f_to_bf(dsc * acc0[r]);
            Gout[(size_t)row * D + (wave * 2 + 1) * 16 + lr] = f_to_bf(dsc * acc1[r]);
        }
    }
}

// ---------------- final aggregation (+ log_softmax) ----------------
template <int MODE>
__global__ __launch_bounds__(256)
void aggregate(const ushort* __restrict__ Gv, const float* __restrict__ dis,
               const int2* __restrict__ bd, const int* __restrict__ col,
               const float* __restrict__ bias, void* __restrict__ outv, int n) {
    int node = blockIdx.x * 16 + (threadIdx.x >> 4);
    if (node >= n) return;
    int lane = threadIdx.x & 15;
    const uint4* base = (const uint4*)Gv;

    uint4 u = base[(size_t)node * 16 + lane];
    float a0 = bf_lo(u.x), a1 = bf_hi(u.x), a2 = bf_lo(u.y), a3 = bf_hi(u.y);
    float a4 = bf_lo(u.z), a5 = bf_hi(u.z), a6 = bf_lo(u.w), a7 = bf_hi(u.w);

    int2 be = bd[node];
    int beg = be.x, end = be.x + be.y;
    int j = beg;
    for (; j + 8 <= end; j += 8) {
        uint4 v0 = base[(size_t)col[j + 0] * 16 + lane];
        uint4 v1 = base[(size_t)col[j + 1] * 16 + lane];
        uint4 v2 = base[(size_t)col[j + 2] * 16 + lane];
        uint4 v3 = base[(size_t)col[j + 3] * 16 + lane];
        uint4 v4 = base[(size_t)col[j + 4] * 16 + lane];
        uint4 v5 = base[(size_t)col[j + 5] * 16 + lane];
        uint4 v6 = base[(size_t)col[j + 6] * 16 + lane];
        uint4 v7 = base[(size_t)col[j + 7] * 16 + lane];
        a0 += bf_lo(v0.x) + bf_lo(v1.x) + bf_lo(v2.x) + bf_lo(v3.x)
            + bf_lo(v4.x) + bf_lo(v5.x) + bf_lo(v6.x) + bf_lo(v7.x);
        a1 += bf_hi(v0.x) + bf_hi(v1.x) + bf_hi(v2.x) + bf_hi(v3.x)
            + bf_hi(v4.x) + bf_hi(v5.x) + bf_hi(v6.x) + bf_hi(v7.x);
        a2 += bf_lo(v0.y) + bf_lo(v1.y) + bf_lo(v2.y) + bf_lo(v3.y)
            + bf_lo(v4.y) + bf_lo(v5.y) + bf_lo(v6.y) + bf_lo(v7.y);
        a3 += bf_hi(v0.y) + bf_hi(v1.y) + bf_hi(v2.y) + bf_hi(v3.y)
            + bf_hi(v4.y) + bf_hi(v5.y) + bf_hi(v6.y) + bf_hi(v7.y);
        a4 += bf_lo(v0.z) + bf_lo(v1.z) + bf_lo(v2.z) + bf_lo(v3.z)
            + bf_lo(v4.z) + bf_lo(v5.z) + bf_lo(v6.z) + bf_lo(v7.z);
        a5 += bf_hi(v0.z) + bf_hi(v1.z) + bf_hi(v2.z) + bf_hi(v3.z)
            + bf_hi(v4.z) + bf_hi(v5.z) + bf_hi(v6.z) + bf_hi(v7.z);
        a6 += bf_lo(v0.w) + bf_lo(v1.w) + bf_lo(v2.w) + bf_lo(v3.w)
            + bf_lo(v4.w) + bf_lo(v5.w) + bf_lo(v6.w) + bf_lo(v7.w);
        a7 += bf_hi(v0.w) + bf_hi(v1.w) + bf_hi(v2.w) + bf_hi(v3.w)
            + bf_hi(v4.w) + bf_hi(v5.w) + bf_hi(v6.w) + bf_hi(v7.w);
    }
    for (; j < end; j++) {
        uint4 v = base[(size_t)col[j] * 16 + lane];
        a0 += bf_lo(v.x); a1 += bf_hi(v.x); a2 += bf_lo(v.y); a3 += bf_hi(v.y);
        a4 += bf_lo(v.z); a5 += bf_hi(v.z); a6 += bf_lo(v.w); a7 += bf_hi(v.w);
    }

    float di = dis[node];
    float4 bA = ((const float4*)bias)[lane * 2];
    float4 bB = ((const float4*)bias)[lane * 2 + 1];
    a0 = fmaxf(di * a0 + bA.x, 0.f); a1 = fmaxf(di * a1 + bA.y, 0.f);
    a2 = fmaxf(di * a2 + bA.z, 0.f); a3 = fmaxf(di * a3 + bA.w, 0.f);
    a4 = fmaxf(di * a4 + bB.x, 0.f); a5 = fmaxf(di * a5 + bB.y, 0.f);
    a6 = fmaxf(di * a6 + bB.z, 0.f); a7 = fmaxf(di * a7 + bB.w, 0.f);

    if (MODE == 1) {
        float m = fmaxf(fmaxf(fmaxf(a0, a1), fmaxf(a2, a3)),
                        fmaxf(fmaxf(a4, a5), fmaxf(a6, a7)));
        for (int off = 8; off > 0; off >>= 1) m = fmaxf(m, __shfl_xor(m, off, 16));
        float e = __expf(a0 - m) + __expf(a1 - m) + __expf(a2 - m) + __expf(a3 - m)
                + __expf(a4 - m) + __expf(a5 - m) + __expf(a6 - m) + __expf(a7 - m);
        for (int off = 8; off > 0; off >>= 1) e += __shfl_xor(e, off, 16);
        float ls = m + __logf(e);
        ((float4*)outv)[(size_t)node * 32 + lane * 2]     = make_float4(a0 - ls, a1 - ls, a2 - ls, a3 - ls);
        ((float4*)outv)[(size_t)node * 32 + lane * 2 + 1] = make_float4(a4 - ls, a5 - ls, a6 - ls, a7 - ls);
    } else {
        ((uint4*)outv)[(size_t)node * 16 + lane] =
            make_uint4(pack_bf2(a0, a1), pack_bf2(a2, a3), pack_bf2(a4, a5), pack_bf2(a6, a7));
    }
}

// ---------------- launcher ----------------

static inline size_t align256(size_t x) { return (x + 255) & ~(size_t)255; }

extern "C" void kernel_launch(void* const* d_in, const int* in_sizes, int n_in,
                              void* d_out, int out_size, void* d_ws, size_t ws_size,
                              hipStream_t stream) {
    const float* x  = (const float*)d_in[0];
    const int*   ei = (const int*)d_in[1];      // int32 (harness-converted)
    const float* W0 = (const float*)d_in[2];
    const float* W1 = (const float*)d_in[3];
    const float* W2 = (const float*)d_in[4];
    const float* b0 = (const float*)d_in[5];
    const float* b1 = (const float*)d_in[6];
    const float* b2 = (const float*)d_in[7];
    float* out      = (float*)d_out;

    const int N = in_sizes[0] / D;
    const int E = in_sizes[1] / 2;
    const int NB = (N + 127) >> 7;              // dst buckets (<= NBMAX)

    // workspace (~60 MB)
    char* ws = (char*)d_ws;
    size_t off = 0;
    float*  dis      = (float*)(ws + off);  off = align256(off + (size_t)N * 4);
    int2*   bd       = (int2*)(ws + off);   off = align256(off + (size_t)N * 8);
    int*    hist     = (int*)(ws + off);    off = align256(off + (size_t)CB * NB * 4);
    int*    btotal   = (int*)(ws + off);    off = align256(off + (size_t)NB * 4);
    int*    bbase    = (int*)(ws + off);    off = align256(off + (size_t)NB * 4);
    int*    cursor   = (int*)(ws + off);    off = align256(off + 4);
    ushort* Wt0      = (ushort*)(ws + off); off = align256(off + (size_t)D * D * 2);
    ushort* Wt1      = (ushort*)(ws + off); off = align256(off + (size_t)D * D * 2);
    ushort* Wt2      = (ushort*)(ws + off); off = align256(off + (size_t)D * D * 2);
    int*    col      = (int*)(ws + off);    off = align256(off + (size_t)E * 4);
    ushort* bufA     = (ushort*)(ws + off); off = align256(off + (size_t)N * D * 2);
    ushort* bufB     = (ushort*)(ws + off); off = align256(off + (size_t)N * D * 2);
    uint*   queue    = (uint*)bufB;         // E*4B = 6.4MB, dead before agg_gemm-1
    (void)ws_size;

    // --- CSR build (histogram sort; ticketed bucket bases) ---
    hist_pass<<<CB, 256, 0, stream>>>(ei, hist, cursor, E, NB);
    col_scan<<<NB, 256, 0, stream>>>(hist, btotal, bbase, cursor, NB);
    scatter_pass<<<CB, 256, 0, stream>>>(ei, hist, bbase, queue, E, NB);
    finalize_pass<<<NB, 256, 0, stream>>>(queue, bbase, btotal, bd, dis, col, N);

    // --- weight conversions (one launch) ---
    convert_w3<<<192, 256, 0, stream>>>(W0, W1, W2, Wt0, Wt1, Wt2);

    const int gemmBlocks = (N + 127) / 128;
    const int fuseBlocks = (N + 15) / 16;

    // --- layer 0 GEMM: x(fp32) @ W0 -> bufA (dis-scaled) ---
    gemm_mfma<1><<<gemmBlocks, 256, 0, stream>>>(x, Wt0, dis, bufA, N);
    // --- fused: agg(bufA)+b0+relu @ W1 -> bufB ---
    agg_gemm<<<fuseBlocks, 256, 0, stream>>>(bufA, dis, bd, col, b0, Wt1, bufB, N);
    // --- fused: agg(bufB)+b1+relu @ W2 -> bufA ---
    agg_gemm<<<fuseBlocks, 256, 0, stream>>>(bufB, dis, bd, col, b1, Wt2, bufA, N);
    // --- final: agg(bufA)+b2+relu+log_softmax -> out (fp32) ---
    aggregate<1><<<fuseBlocks, 256, 0, stream>>>(bufA, dis, bd, col, b2, out, N);
}

// Round 6
// 408.884 us; speedup vs baseline: 1.3125x; 1.0343x over previous
//
#include <hip/hip_runtime.h>
#include <cstdint>

// ---------------------------------------------------------------------------
// GCN: 3 x [ h = relu( Ahat (h W) + b ) ], then log_softmax.
// Round 16: split pipeline (fusion dead: r13 -24us/pair @36KB LDS, r15 break-
// even @4KB LDS -- barrier couples gather tails regardless of occupancy).
// Target: CSR build (est ~115us by subtraction). Root cause: hist/scatter ran
// 256 blocks = 1 block/CU = 12.5% occupancy, latency-starved LDS-atomic
// chains (same disease as r14's cooperative attempt). Fix: CB=768 chunks
// (3 blocks/CU), col_scan handles 3 chunk-entries/thread, convert_w3 folded
// into the hist launch. Aggregate/gemm are the verified r12 kernels.
// Lessons kept: no returned global atomics (r11), no 36KB-LDS fusion (r13),
// no cooperative launch (r14), no agg+gemm fusion (r15).
// edge_index arrives as int32 (harness converts integer inputs).
// ---------------------------------------------------------------------------

#define D 128
#define NBMAX 800      // max dst buckets of 128 nodes (N <= 102400)
#define QCAP 4608      // LDS staging capacity per bucket in finalize
#define CB 768         // histogram/scatter chunks (3 blocks/CU)

typedef __attribute__((ext_vector_type(8))) short bf16x8;
typedef __attribute__((ext_vector_type(4))) float f32x4;

__device__ inline ushort f_to_bf(float f) {
    uint x = __float_as_uint(f);
    return (ushort)((x + 0x7fffu + ((x >> 16) & 1u)) >> 16);   // RNE
}
__device__ inline uint pack_bf2(float a, float b) {
    return (uint)f_to_bf(a) | ((uint)f_to_bf(b) << 16);
}
__device__ inline float bf_lo(uint u) { return __uint_as_float(u << 16); }
__device__ inline float bf_hi(uint u) { return __uint_as_float(u & 0xffff0000u); }

// ---------------- CSR build (histogram sort; LDS atomics only) -------------

// blocks [0,CB): per-chunk dst-bucket histogram. blocks [CB,CB+192): W->Wt.
__global__ void hist_conv(const int* __restrict__ ei, int* __restrict__ hist,
                          int* __restrict__ cursor, int E, int NB,
                          const float* __restrict__ W0, const float* __restrict__ W1,
                          const float* __restrict__ W2, ushort* __restrict__ Wt0,
                          ushort* __restrict__ Wt1, ushort* __restrict__ Wt2) {
    int b = blockIdx.x;
    if (b >= CB) {   // weight conversion tail
        int bb = b - CB;
        int which = bb >> 6;   // 64 blocks (16384 elems) per weight
        int i = (bb & 63) * 256 + threadIdx.x;
        const float* W = which == 0 ? W0 : (which == 1 ? W1 : W2);
        ushort* Wt = which == 0 ? Wt0 : (which == 1 ? Wt1 : Wt2);
        Wt[(i & 127) * D + (i >> 7)] = f_to_bf(W[i]);
        return;
    }
    __shared__ int lh[NBMAX];
    if (b == 0 && threadIdx.x == 0) *cursor = 0;
    for (int i = threadIdx.x; i < NB; i += 256) lh[i] = 0;
    __syncthreads();
    int CE = (E + CB - 1) / CB;
    int e0 = b * CE, e1 = min(e0 + CE, E);
    for (int e = e0 + threadIdx.x; e < e1; e += 256)
        atomicAdd(&lh[ei[(size_t)E + e] >> 7], 1);
    __syncthreads();
    int* hrow = hist + (size_t)b * NB;
    for (int i = threadIdx.x; i < NB; i += 256) hrow[i] = lh[i];
}

// per-bucket exclusive scan over CB chunk counts (3 per thread) + base ticket.
// Bucket regions are disjoint, in ARBITRARY order (fine: consumers use
// per-node (beg,deg) from bd[], never cross-bucket contiguity).
__global__ void col_scan(int* __restrict__ hist, int* __restrict__ btotal,
                         int* __restrict__ bbase, int* __restrict__ cursor, int NB) {
    __shared__ int s[256];
    int g = blockIdx.x, t = threadIdx.x;
    int v[3];
    int sum = 0;
#pragma unroll
    for (int i = 0; i < 3; i++) {
        v[i] = hist[(size_t)(t * 3 + i) * NB + g];
        sum += v[i];
    }
    s[t] = sum;
    __syncthreads();
    for (int off = 1; off < 256; off <<= 1) {
        int u = (t >= off) ? s[t - off] : 0;
        __syncthreads();
        s[t] += u;
        __syncthreads();
    }
    int excl = s[t] - sum;
#pragma unroll
    for (int i = 0; i < 3; i++) {
        hist[(size_t)(t * 3 + i) * NB + g] = excl;
        excl += v[i];
    }
    if (t == 255) { btotal[g] = s[255]; bbase[g] = atomicAdd(cursor, s[255]); }
}

__global__ void scatter_pass(const int* __restrict__ ei, const int* __restrict__ hist,
                             const int* __restrict__ bbase, uint* __restrict__ queue,
                             int E, int NB) {
    __shared__ int loff[NBMAX];
    const int* hrow = hist + (size_t)blockIdx.x * NB;
    for (int i = threadIdx.x; i < NB; i += 256) loff[i] = bbase[i] + hrow[i];
    __syncthreads();
    int CE = (E + CB - 1) / CB;
    int e0 = blockIdx.x * CE, e1 = min(e0 + CE, E);
    for (int e = e0 + threadIdx.x; e < e1; e += 256) {
        int d = ei[(size_t)E + e];
        int s = ei[e];
        int slot = atomicAdd(&loff[d >> 7], 1);       // LDS atomic
        queue[slot] = ((uint)(d & 127) << 17) | (uint)s;   // needs N <= 131072
    }
}

__global__ void finalize_pass(const uint* __restrict__ queue, const int* __restrict__ bbase,
                              const int* __restrict__ btotal, int2* __restrict__ bd,
                              float* __restrict__ dis, int* __restrict__ col, int N) {
    __shared__ uint qs[QCAP];
    __shared__ int cnt[128], pre[128], run[128];
    int g = blockIdx.x, t = threadIdx.x;
    int base = bbase[g], m = btotal[g];
    bool fits = (m <= QCAP);
    if (t < 128) { cnt[t] = 0; run[t] = 0; }
    __syncthreads();
    for (int i = t; i < m; i += 256) {
        uint e = queue[base + i];
        if (fits) qs[i] = e;
        atomicAdd(&cnt[e >> 17], 1);                  // LDS atomic
    }
    __syncthreads();
    if (t < 128) pre[t] = cnt[t];
    __syncthreads();
    for (int off = 1; off < 128; off <<= 1) {
        int u = (t < 128 && t >= off) ? pre[t - off] : 0;
        __syncthreads();
        if (t < 128) pre[t] += u;                     // inclusive scan
        __syncthreads();
    }
    if (t < 128) {
        int node = (g << 7) + t;
        if (node < N) {
            bd[node] = make_int2(base + pre[t] - cnt[t], cnt[t]);
            dis[node] = rsqrtf((float)(cnt[t] + 1));  // self loop -> deg >= 1
        }
    }
    __syncthreads();
    for (int i = t; i < m; i += 256) {
        uint e = fits ? qs[i] : queue[base + i];
        int idx = (int)(e >> 17);
        int r = atomicAdd(&run[idx], 1);              // LDS atomic
        col[base + pre[idx] - cnt[idx] + r] = (int)(e & 0x1FFFFu);
    }
}

// ---------------- GEMM: G[n,128] = dis[row] * (X[n,128] @ W), MFMA ----------
// 256 threads = 4 waves; wave computes 32 rows x 128 cols. Wt staged once per
// block into LDS in frag-major swizzled order (lane-contiguous ds_read_b128).
template <int F32IN>
__global__ __launch_bounds__(256)
void gemm_mfma(const void* __restrict__ Xv, const ushort* __restrict__ Wt,
               const float* __restrict__ dis, ushort* __restrict__ G, int n) {
    __shared__ ushort Bs[32 * 64 * 8];   // 32 KB
    int tid = threadIdx.x;
    int wave = tid >> 6, lane = tid & 63;
    int lr = lane & 15, quad = lane >> 4;
    int rowbase = blockIdx.x * 128 + wave * 32;

    for (int s = tid; s < 2048; s += 256) {
        int g = s >> 6, l = s & 63;
        int kk = g >> 3, nt = g & 7;
        int srow = nt * 16 + (l & 15);
        int scol = kk * 32 + (l >> 4) * 8;
        ((uint4*)Bs)[s] = *(const uint4*)(Wt + srow * D + scol);
    }
    __syncthreads();

    int ar0 = min(rowbase + lr, n - 1);
    int ar1 = min(rowbase + 16 + lr, n - 1);

    f32x4 acc[2][8];
#pragma unroll
    for (int rt = 0; rt < 2; rt++)
#pragma unroll
        for (int nt = 0; nt < 8; nt++) acc[rt][nt] = (f32x4){0.f, 0.f, 0.f, 0.f};

#pragma unroll
    for (int kk = 0; kk < 4; kk++) {
        bf16x8 a0, a1;
        if (F32IN) {
            const float* X = (const float*)Xv;
            const float* p0 = X + (size_t)ar0 * D + kk * 32 + quad * 8;
            const float* p1 = X + (size_t)ar1 * D + kk * 32 + quad * 8;
            float4 u0 = ((const float4*)p0)[0], v0 = ((const float4*)p0)[1];
            float4 u1 = ((const float4*)p1)[0], v1 = ((const float4*)p1)[1];
            a0 = (bf16x8){(short)f_to_bf(u0.x), (short)f_to_bf(u0.y), (short)f_to_bf(u0.z), (short)f_to_bf(u0.w),
                          (short)f_to_bf(v0.x), (short)f_to_bf(v0.y), (short)f_to_bf(v0.z), (short)f_to_bf(v0.w)};
            a1 = (bf16x8){(short)f_to_bf(u1.x), (short)f_to_bf(u1.y), (short)f_to_bf(u1.z), (short)f_to_bf(u1.w),
                          (short)f_to_bf(v1.x), (short)f_to_bf(v1.y), (short)f_to_bf(v1.z), (short)f_to_bf(v1.w)};
        } else {
            const ushort* X = (const ushort*)Xv;
            a0 = ((const bf16x8*)(X + (size_t)ar0 * D))[kk * 4 + quad];
            a1 = ((const bf16x8*)(X + (size_t)ar1 * D))[kk * 4 + quad];
        }
#pragma unroll
        for (int nt = 0; nt < 8; nt++) {
            bf16x8 b = ((const bf16x8*)Bs)[(kk * 8 + nt) * 64 + lane];
            acc[0][nt] = __builtin_amdgcn_mfma_f32_16x16x32_bf16(a0, b, acc[0][nt], 0, 0, 0);
            acc[1][nt] = __builtin_amdgcn_mfma_f32_16x16x32_bf16(a1, b, acc[1][nt], 0, 0, 0);
        }
    }

#pragma unroll
    for (int rt = 0; rt < 2; rt++) {
#pragma unroll
        for (int r = 0; r < 4; r++) {
            int row = rowbase + rt * 16 + quad * 4 + r;
            if (row < n) {
                float dsc = dis[row];
#pragma unroll
                for (int nt = 0; nt < 8; nt++)
                    G[(size_t)row * D + nt * 16 + lr] = f_to_bf(dsc * acc[rt][nt][r]);
            }
        }
    }
}

// ---------------- Aggregation ----------------
// G rows pre-scaled by dis[src]. out[i] = act( dis[i]*(sum G[s] + G[i]) + b ).
// QUARTER-wave (16 lanes x uint4 = 8 bf16) per node; edge loop unrolled x8
// -> 8 KB of gathers in flight per wave. MODE 0: relu->bf16. MODE 1: +lsm->f32.
template <int MODE>
__global__ __launch_bounds__(256)
void aggregate(const ushort* __restrict__ Gv, const float* __restrict__ dis,
               const int2* __restrict__ bd, const int* __restrict__ col,
               const float* __restrict__ bias, void* __restrict__ outv, int n) {
    int node = blockIdx.x * 16 + (threadIdx.x >> 4);
    if (node >= n) return;
    int lane = threadIdx.x & 15;
    const uint4* base = (const uint4*)Gv;

    uint4 u = base[(size_t)node * 16 + lane];
    float a0 = bf_lo(u.x), a1 = bf_hi(u.x), a2 = bf_lo(u.y), a3 = bf_hi(u.y);
    float a4 = bf_lo(u.z), a5 = bf_hi(u.z), a6 = bf_lo(u.w), a7 = bf_hi(u.w);

    int2 be = bd[node];
    int beg = be.x, end = be.x + be.y;
    int j = beg;
    for (; j + 8 <= end; j += 8) {
        uint4 v0 = base[(size_t)col[j + 0] * 16 + lane];
        uint4 v1 = base[(size_t)col[j + 1] * 16 + lane];
        uint4 v2 = base[(size_t)col[j + 2] * 16 + lane];
        uint4 v3 = base[(size_t)col[j + 3] * 16 + lane];
        uint4 v4 = base[(size_t)col[j + 4] * 16 + lane];
        uint4 v5 = base[(size_t)col[j + 5] * 16 + lane];
        uint4 v6 = base[(size_t)col[j + 6] * 16 + lane];
        uint4 v7 = base[(size_t)col[j + 7] * 16 + lane];
        a0 += bf_lo(v0.x) + bf_lo(v1.x) + bf_lo(v2.x) + bf_lo(v3.x)
            + bf_lo(v4.x) + bf_lo(v5.x) + bf_lo(v6.x) + bf_lo(v7.x);
        a1 += bf_hi(v0.x) + bf_hi(v1.x) + bf_hi(v2.x) + bf_hi(v3.x)
            + bf_hi(v4.x) + bf_hi(v5.x) + bf_hi(v6.x) + bf_hi(v7.x);
        a2 += bf_lo(v0.y) + bf_lo(v1.y) + bf_lo(v2.y) + bf_lo(v3.y)
            + bf_lo(v4.y) + bf_lo(v5.y) + bf_lo(v6.y) + bf_lo(v7.y);
        a3 += bf_hi(v0.y) + bf_hi(v1.y) + bf_hi(v2.y) + bf_hi(v3.y)
            + bf_hi(v4.y) + bf_hi(v5.y) + bf_hi(v6.y) + bf_hi(v7.y);
        a4 += bf_lo(v0.z) + bf_lo(v1.z) + bf_lo(v2.z) + bf_lo(v3.z)
            + bf_lo(v4.z) + bf_lo(v5.z) + bf_lo(v6.z) + bf_lo(v7.z);
        a5 += bf_hi(v0.z) + bf_hi(v1.z) + bf_hi(v2.z) + bf_hi(v3.z)
            + bf_hi(v4.z) + bf_hi(v5.z) + bf_hi(v6.z) + bf_hi(v7.z);
        a6 += bf_lo(v0.w) + bf_lo(v1.w) + bf_lo(v2.w) + bf_lo(v3.w)
            + bf_lo(v4.w) + bf_lo(v5.w) + bf_lo(v6.w) + bf_lo(v7.w);
        a7 += bf_hi(v0.w) + bf_hi(v1.w) + bf_hi(v2.w) + bf_hi(v3.w)
            + bf_hi(v4.w) + bf_hi(v5.w) + bf_hi(v6.w) + bf_hi(v7.w);
    }
    for (; j < end; j++) {
        uint4 v = base[(size_t)col[j] * 16 + lane];
        a0 += bf_lo(v.x); a1 += bf_hi(v.x); a2 += bf_lo(v.y); a3 += bf_hi(v.y);
        a4 += bf_lo(v.z); a5 += bf_hi(v.z); a6 += bf_lo(v.w); a7 += bf_hi(v.w);
    }

    float di = dis[node];
    float4 bA = ((const float4*)bias)[lane * 2];
    float4 bB = ((const float4*)bias)[lane * 2 + 1];
    a0 = fmaxf(di * a0 + bA.x, 0.f); a1 = fmaxf(di * a1 + bA.y, 0.f);
    a2 = fmaxf(di * a2 + bA.z, 0.f); a3 = fmaxf(di * a3 + bA.w, 0.f);
    a4 = fmaxf(di * a4 + bB.x, 0.f); a5 = fmaxf(di * a5 + bB.y, 0.f);
    a6 = fmaxf(di * a6 + bB.z, 0.f); a7 = fmaxf(di * a7 + bB.w, 0.f);

    if (MODE == 1) {
        float m = fmaxf(fmaxf(fmaxf(a0, a1), fmaxf(a2, a3)),
                        fmaxf(fmaxf(a4, a5), fmaxf(a6, a7)));
        for (int off = 8; off > 0; off >>= 1) m = fmaxf(m, __shfl_xor(m, off, 16));
        float e = __expf(a0 - m) + __expf(a1 - m) + __expf(a2 - m) + __expf(a3 - m)
                + __expf(a4 - m) + __expf(a5 - m) + __expf(a6 - m) + __expf(a7 - m);
        for (int off = 8; off > 0; off >>= 1) e += __shfl_xor(e, off, 16);
        float ls = m + __logf(e);
        ((float4*)outv)[(size_t)node * 32 + lane * 2]     = make_float4(a0 - ls, a1 - ls, a2 - ls, a3 - ls);
        ((float4*)outv)[(size_t)node * 32 + lane * 2 + 1] = make_float4(a4 - ls, a5 - ls, a6 - ls, a7 - ls);
    } else {
        ((uint4*)outv)[(size_t)node * 16 + lane] =
            make_uint4(pack_bf2(a0, a1), pack_bf2(a2, a3), pack_bf2(a4, a5), pack_bf2(a6, a7));
    }
}

// ---------------- launcher ----------------

static inline size_t align256(size_t x) { return (x + 255) & ~(size_t)255; }

extern "C" void kernel_launch(void* const* d_in, const int* in_sizes, int n_in,
                              void* d_out, int out_size, void* d_ws, size_t ws_size,
                              hipStream_t stream) {
    const float* x  = (const float*)d_in[0];
    const int*   ei = (const int*)d_in[1];      // int32 (harness-converted)
    const float* W0 = (const float*)d_in[2];
    const float* W1 = (const float*)d_in[3];
    const float* W2 = (const float*)d_in[4];
    const float* b0 = (const float*)d_in[5];
    const float* b1 = (const float*)d_in[6];
    const float* b2 = (const float*)d_in[7];
    float* out      = (float*)d_out;

    const int N = in_sizes[0] / D;
    const int E = in_sizes[1] / 2;
    const int NB = (N + 127) >> 7;              // dst buckets (<= NBMAX)

    // workspace (~62 MB)
    char* ws = (char*)d_ws;
    size_t off = 0;
    float*  dis      = (float*)(ws + off);  off = align256(off + (size_t)N * 4);
    int2*   bd       = (int2*)(ws + off);   off = align256(off + (size_t)N * 8);
    int*    hist     = (int*)(ws + off);    off = align256(off + (size_t)CB * NB * 4);
    int*    btotal   = (int*)(ws + off);    off = align256(off + (size_t)NB * 4);
    int*    bbase    = (int*)(ws + off);    off = align256(off + (size_t)NB * 4);
    int*    cursor   = (int*)(ws + off);    off = align256(off + 4);
    ushort* Wt0      = (ushort*)(ws + off); off = align256(off + (size_t)D * D * 2);
    ushort* Wt1      = (ushort*)(ws + off); off = align256(off + (size_t)D * D * 2);
    ushort* Wt2      = (ushort*)(ws + off); off = align256(off + (size_t)D * D * 2);
    int*    col      = (int*)(ws + off);    off = align256(off + (size_t)E * 4);
    ushort* bufA     = (ushort*)(ws + off); off = align256(off + (size_t)N * D * 2);
    ushort* bufB     = (ushort*)(ws + off); off = align256(off + (size_t)N * D * 2);
    ushort* dhead    = (ushort*)d_out;      // 25.6 MB of d_out; dead before final write
    uint*   queue    = (uint*)bufB;         // E*4B = 6.4MB, dead before gemm layer-1
    (void)ws_size;

    // --- CSR build (histogram sort; 3 blocks/CU for the edge passes) ---
    hist_conv<<<CB + 192, 256, 0, stream>>>(ei, hist, cursor, E, NB,
                                            W0, W1, W2, Wt0, Wt1, Wt2);
    col_scan<<<NB, 256, 0, stream>>>(hist, btotal, bbase, cursor, NB);
    scatter_pass<<<CB, 256, 0, stream>>>(ei, hist, bbase, queue, E, NB);
    finalize_pass<<<NB, 256, 0, stream>>>(queue, bbase, btotal, bd, dis, col, N);

    const int gemmBlocks = (N + 127) / 128;
    const int aggBlocks  = (N + 15) / 16;

    // --- layer 0: x(fp32) @ W0 -> dhead; agg -> bufA ---
    gemm_mfma<1><<<gemmBlocks, 256, 0, stream>>>(x, Wt0, dis, dhead, N);
    aggregate<0><<<aggBlocks, 256, 0, stream>>>(dhead, dis, bd, col, b0, bufA, N);
    // --- layer 1: bufA @ W1 -> bufB; agg -> dhead ---
    gemm_mfma<0><<<gemmBlocks, 256, 0, stream>>>(bufA, Wt1, dis, bufB, N);
    aggregate<0><<<aggBlocks, 256, 0, stream>>>(bufB, dis, bd, col, b1, dhead, N);
    // --- layer 2: dhead @ W2 -> bufA; agg + log_softmax -> out ---
    gemm_mfma<0><<<gemmBlocks, 256, 0, stream>>>(dhead, Wt2, dis, bufA, N);
    aggregate<1><<<aggBlocks, 256, 0, stream>>>(bufA, dis, bd, col, b2, out, N);
}